// Round 3
// baseline (313.240 us; speedup 1.0000x reference)
//
#include <hip/hip_runtime.h>
#include <hip/hip_bf16.h>
#include <stdint.h>

typedef unsigned short u16;
typedef __attribute__((ext_vector_type(4))) unsigned short u16x4;
typedef __attribute__((ext_vector_type(8))) short short8;
typedef __attribute__((ext_vector_type(4))) float f32x4;

__device__ inline u16 f2b(float f) {
  uint32_t u = __builtin_bit_cast(uint32_t, f);
  u += 0x7fffu + ((u >> 16) & 1u);   // RNE round to bf16
  return (u16)(u >> 16);
}
__device__ inline float b2f(u16 b) {
  return __builtin_bit_cast(float, (uint32_t)b << 16);
}

// ---------------- fused prep: x->bf16, W transpose+cvt, bias concat, rowsum zero --------
__global__ __launch_bounds__(256) void prep(
    const float* __restrict__ x, u16* __restrict__ xb,
    const float* __restrict__ Wq, const float* __restrict__ Wk,
    const float* __restrict__ Wv, u16* __restrict__ wT,
    const float* __restrict__ bq, const float* __restrict__ bk,
    const float* __restrict__ bv, float* __restrict__ biasC,
    float* __restrict__ rowsum) {
  __shared__ float tl[32][33];
  const int b = blockIdx.x;
  const int t = threadIdx.x;
  if (b < 8192) {
    long i = ((long)b * 256 + t) * 4;
    float4 v = *(const float4*)(x + i);
    u16x4 o = { f2b(v.x), f2b(v.y), f2b(v.z), f2b(v.w) };
    *(u16x4*)(xb + i) = o;
  } else if (b < 8192 + 3072) {
    const int bb = b - 8192;
    const int z = bb >> 10;            // 0..2 -> Wq/Wk/Wv
    const int tile = bb & 1023;
    const float* in = z == 0 ? Wq : (z == 1 ? Wk : Wv);
    u16* o = wT + (long)z * 1024 * 1024;
    const int c0 = (tile & 31) * 32, r0 = (tile >> 5) * 32;
    const int tx = t & 31, ty = t >> 5;   // 32 x 8
#pragma unroll
    for (int j = 0; j < 32; j += 8)
      tl[ty + j][tx] = in[(long)(r0 + ty + j) * 1024 + c0 + tx];
    __syncthreads();
#pragma unroll
    for (int j = 0; j < 32; j += 8)
      o[(long)(c0 + ty + j) * 1024 + r0 + tx] = f2b(tl[tx][ty + j]);
  } else {
    const int i = (b - 8192 - 3072) * 256 + t;
    if (i < 3072)
      biasC[i] = i < 1024 ? bq[i] : (i < 2048 ? bk[i - 1024] : bv[i - 2048]);
    else if (i < 3072 + 8192)
      rowsum[i - 3072] = 0.0f;
  }
}

__device__ inline void load_lds16(const void* g, void* l) {
  __builtin_amdgcn_global_load_lds((const __attribute__((address_space(1))) void*)g,
                                   (__attribute__((address_space(3))) void*)l, 16, 0, 0);
}

#define BAR  asm volatile("s_barrier" ::: "memory")
#define LGK0 asm volatile("s_waitcnt lgkmcnt(0)" ::: "memory")
#define VM4  asm volatile("s_waitcnt vmcnt(4)" ::: "memory")

// 16-MFMA cluster: quadrant (IH,JH) of the per-wave 8x4 fragment grid, full K=64
#define MM(IH, JH) do {                                                        \
  __builtin_amdgcn_s_setprio(1);                                               \
  _Pragma("unroll")                                                            \
  for (int i_ = 0; i_ < 4; i_++)                                               \
    _Pragma("unroll")                                                          \
    for (int j_ = 0; j_ < 2; j_++)                                             \
      _Pragma("unroll")                                                        \
      for (int kk_ = 0; kk_ < 2; kk_++)                                        \
        acc[(IH)*4 + i_][(JH)*2 + j_] = __builtin_amdgcn_mfma_f32_16x16x32_bf16( \
            aF[i_][kk_], bF[j_][kk_], acc[(IH)*4 + i_][(JH)*2 + j_], 0, 0, 0); \
  __builtin_amdgcn_s_setprio(0);                                               \
} while (0)

// ---------------- 256x256 8-phase bt-GEMM (T2+T3+T4+T5), 512 threads ----------------
// C[m][n] = sum_k A[m][k]*Bt[n][k].  8 waves = 2(M) x 4(N); per-wave 128x64 out.
// LDS: double-buffered A[256][64] + B[256][64] bf16 = 128 KB, chunk-XOR swizzled
// (slot s of row r holds global chunk s^(r&7); staged linear-dest + preswizzled src).
// Stage units (2 x global_load_lds/thread each): A0 = A-rows {0-63,128-191},
// A1 = {64-127,192-255}; B0 = B-rows {q*64+0..31}, B1 = {q*64+32..63}.
// Per K-tile 4 phases (Q00,Q01,Q11,Q10); 2 K-tiles/iter; one stage unit issued
// per phase for the tile-after-next's buffer; counted vmcnt(4) before the barrier
// at phase ends P1,P2,P4,P5,P6,P8 (reads of phase p+1 need units issued >=4 earlier).
// MODE 0: QKV epilogue (bias; V cols pre-transposed into Vt)
// MODE 2: scores epilogue: P = exp(v*scale + mask) bf16, rowsum += partials
template <int MODE>
__global__ __launch_bounds__(512, 1) void gemm8(
    const u16* __restrict__ A, const u16* __restrict__ Bt, void* __restrict__ C,
    u16* __restrict__ vtOut, const float* __restrict__ bias,
    float* __restrict__ rsum, const float* __restrict__ maskG,
    int K, int lda, int ldb, int ldc,
    long sA_, long sB_, long sC_, float scale)
{
  const int z = blockIdx.z;
  A += z * sA_;
  Bt += z * sB_;
  const long cbase = z * sC_;

  __shared__ __align__(16) u16 sA[2][256 * 64];   // 64 KB
  __shared__ __align__(16) u16 sB[2][256 * 64];   // 64 KB

  const int t = threadIdx.x;
  const int lane = t & 63, wave = t >> 6;
  const int wr = wave >> 2, wc = wave & 3;        // 2 x 4 wave grid
  const int fr = lane & 15, q4 = lane >> 4;
  const int m0 = blockIdx.y * 256, n0 = blockIdx.x * 256;
  const int nT = K / 64;

  auto stA = [&](int half, int kt, int buf) {
    if (kt >= nT) kt = 0;                          // tail clamp (staged, never read)
    const long ko = (long)kt * 64;
#pragma unroll
    for (int ii = 0; ii < 2; ii++) {
      int c = ii * 512 + t;
      int rr = c >> 3, slot = c & 7;
      int row = (rr < 64) ? (half * 64 + rr) : (128 + half * 64 + rr - 64);
      int gch = slot ^ (row & 7);
      load_lds16(A + (long)(m0 + row) * lda + ko + gch * 8,
                 &sA[buf][row * 64 + slot * 8]);
    }
  };
  auto stB = [&](int half, int kt, int buf) {
    if (kt >= nT) kt = 0;
    const long ko = (long)kt * 64;
#pragma unroll
    for (int ii = 0; ii < 2; ii++) {
      int c = ii * 512 + t;
      int rr = c >> 3, slot = c & 7;
      int row = (rr >> 5) * 64 + half * 32 + (rr & 31);
      int gch = slot ^ (row & 7);
      load_lds16(Bt + (long)(n0 + row) * ldb + ko + gch * 8,
                 &sB[buf][row * 64 + slot * 8]);
    }
  };

  short8 aF[4][2], bF[2][2];
  f32x4 acc[8][4] = {};

  auto rdA = [&](int half, int buf) {
#pragma unroll
    for (int i = 0; i < 4; i++) {
      int row = wr * 128 + half * 64 + i * 16 + fr;
#pragma unroll
      for (int kk = 0; kk < 2; kk++) {
        int ch = kk * 4 + q4;
        aF[i][kk] = *(const short8*)&sA[buf][row * 64 + ((ch ^ (row & 7)) * 8)];
      }
    }
  };
  auto rdB = [&](int half, int buf) {
#pragma unroll
    for (int j = 0; j < 2; j++) {
      int row = wc * 64 + half * 32 + j * 16 + fr;
#pragma unroll
      for (int kk = 0; kk < 2; kk++) {
        int ch = kk * 4 + q4;
        bF[j][kk] = *(const short8*)&sB[buf][row * 64 + ((ch ^ (row & 7)) * 8)];
      }
    }
  };

  // prologue: tile 0 -> buf0, stage order A0,B0,B1,A1; wait so A0,B0 are landed
  stA(0, 0, 0); stB(0, 0, 0); stB(1, 0, 0); stA(1, 0, 0);
  VM4; BAR;

  const int nIt = nT / 2;
#pragma unroll 1
  for (int it = 0; it < nIt; ++it) {
    const int kt = 2 * it;
    // ---- tile kt (buf0), staging tile kt+1 -> buf1 ----
    rdA(0, 0); rdB(0, 0); stA(0, kt + 1, 1);
    BAR; LGK0; MM(0, 0); VM4; BAR;          // P1
    rdB(1, 0);            stB(0, kt + 1, 1);
    BAR; LGK0; MM(0, 1); VM4; BAR;          // P2
    rdA(1, 0);            stB(1, kt + 1, 1);
    BAR; LGK0; MM(1, 1);      BAR;          // P3
    rdB(0, 0);            stA(1, kt + 1, 1);
    BAR; LGK0; MM(1, 0); VM4; BAR;          // P4
    // ---- tile kt+1 (buf1), staging tile kt+2 -> buf0 ----
    rdA(0, 1); rdB(0, 1); stA(0, kt + 2, 0);
    BAR; LGK0; MM(0, 0); VM4; BAR;          // P5
    rdB(1, 1);            stB(0, kt + 2, 0);
    BAR; LGK0; MM(0, 1); VM4; BAR;          // P6
    rdA(1, 1);            stB(1, kt + 2, 0);
    BAR; LGK0; MM(1, 1);      BAR;          // P7
    rdB(0, 1);            stA(1, kt + 2, 0);
    BAR; LGK0; MM(1, 0); VM4; BAR;          // P8
  }

  // epilogue: C/D layout col = lane&15, row = (lane>>4)*4 + r
  if (MODE == 2) {
    const float* mk = maskG + (long)z * 2048 * 2048;
    u16* Pout = (u16*)C + cbase;
    float* rz = rsum + (long)z * 2048;
#pragma unroll
    for (int i = 0; i < 8; i++) {
      const int row = m0 + wr * 128 + i * 16 + q4 * 4;
      float ml[4][4];
#pragma unroll
      for (int j = 0; j < 4; j++) {
        const int col = n0 + wc * 64 + j * 16 + fr;
#pragma unroll
        for (int r = 0; r < 4; r++)
          ml[j][r] = mk[(long)(row + r) * 2048 + col];   // batched: 16 loads in flight
      }
      float rs[4] = {0.f, 0.f, 0.f, 0.f};
#pragma unroll
      for (int j = 0; j < 4; j++) {
        const int col = n0 + wc * 64 + j * 16 + fr;
#pragma unroll
        for (int r = 0; r < 4; r++) {
          float e = __expf(acc[i][j][r] * scale + ml[j][r]);
          Pout[(long)(row + r) * ldc + col] = f2b(e);
          rs[r] += e;
        }
      }
#pragma unroll
      for (int r = 0; r < 4; r++) {
        float s = rs[r];
        s += __shfl_xor(s, 1); s += __shfl_xor(s, 2);
        s += __shfl_xor(s, 4); s += __shfl_xor(s, 8);
        if (fr == 0) atomicAdd(&rz[row + r], s);
      }
    }
  } else {
#pragma unroll
    for (int i = 0; i < 8; i++) {
#pragma unroll
      for (int j = 0; j < 4; j++) {
        const int row = m0 + wr * 128 + i * 16 + q4 * 4;
        const int col = n0 + wc * 64 + j * 16 + fr;
        const float b = bias[col];
        if (col >= 2048) {
          u16x4 o = { f2b(acc[i][j][0] + b), f2b(acc[i][j][1] + b),
                      f2b(acc[i][j][2] + b), f2b(acc[i][j][3] + b) };
          *(u16x4*)(vtOut + (long)(col - 2048) * 8192 + row) = o;
        } else {
#pragma unroll
          for (int r = 0; r < 4; r++)
            ((u16*)C)[(long)(row + r) * ldc + col] = f2b(acc[i][j][r] + b);
        }
      }
    }
  }
}

// ---------------- PV: proven 128x128 kernel, deferred-normalization epilogue ----------------
#define BM 128
#define BN 128
#define BK 64

__global__ __launch_bounds__(256, 2) void gemm_pv(
    const u16* __restrict__ A, const u16* __restrict__ Bt, float* __restrict__ C,
    const float* __restrict__ rsum,
    int K, int lda, int ldb, int ldc, long sA_, long sB_, long sC_)
{
  const int z = blockIdx.z;
  A += z * sA_;
  Bt += z * sB_;
  const long cbase = z * sC_;

  __shared__ __align__(16) u16 lA[BM * BK];
  __shared__ __align__(16) u16 lB[BN * BK];

  const int t = threadIdx.x;
  const int lane = t & 63;
  const int wave = t >> 6;
  const int wr = wave >> 1, wc = wave & 1;
  const int m0 = blockIdx.y * BM, n0 = blockIdx.x * BN;

  const int srow = t >> 3;
  const int schunk = (t & 7) ^ (srow & 7);
  const u16* aS = A + (long)(m0 + srow) * lda + schunk * 8;
  const u16* bS = Bt + (long)(n0 + srow) * ldb + schunk * 8;

  f32x4 acc[4][4] = {};
  const int fr = lane & 15;
  const int q4 = lane >> 4;

  for (int k0 = 0; k0 < K; k0 += BK) {
    __syncthreads();
#pragma unroll
    for (int i = 0; i < 4; i++) {
      load_lds16(aS + k0 + (long)(i * 32) * lda, &lA[(i * 256 + t) * 8]);
      load_lds16(bS + k0 + (long)(i * 32) * ldb, &lB[(i * 256 + t) * 8]);
    }
    __syncthreads();
#pragma unroll
    for (int kk = 0; kk < 2; kk++) {
      const int ch = kk * 4 + q4;
      short8 aF[4], bF[4];
#pragma unroll
      for (int i = 0; i < 4; i++) {
        int row = wr * 64 + i * 16 + fr;
        aF[i] = *(const short8*)&lA[row * BK + ((ch ^ (row & 7)) * 8)];
      }
#pragma unroll
      for (int j = 0; j < 4; j++) {
        int row = wc * 64 + j * 16 + fr;
        bF[j] = *(const short8*)&lB[row * BK + ((ch ^ (row & 7)) * 8)];
      }
#pragma unroll
      for (int i = 0; i < 4; i++)
#pragma unroll
        for (int j = 0; j < 4; j++)
          acc[i][j] = __builtin_amdgcn_mfma_f32_16x16x32_bf16(aF[i], bF[j], acc[i][j], 0, 0, 0);
    }
  }

  const int r0 = q4 * 4;
  const float* lz = rsum + (long)z * 2048;
#pragma unroll
  for (int i = 0; i < 4; i++) {
    const int row = m0 + wr * 64 + i * 16 + r0;
    float inv[4];
#pragma unroll
    for (int r = 0; r < 4; r++) inv[r] = 1.0f / lz[row + r];
#pragma unroll
    for (int j = 0; j < 4; j++) {
      const int col = n0 + wc * 64 + j * 16 + fr;
#pragma unroll
      for (int r = 0; r < 4; r++)
        C[cbase + (long)(row + r) * ldc + col] = acc[i][j][r] * inv[r];
    }
  }
}

// ---------------- launch ----------------
extern "C" void kernel_launch(void* const* d_in, const int* in_sizes, int n_in,
                              void* d_out, int out_size, void* d_ws, size_t ws_size,
                              hipStream_t stream) {
  const float* x    = (const float*)d_in[0];   // [4,2048,1024]
  const float* mask = (const float*)d_in[1];   // [4,2048,2048]
  const float* Wq   = (const float*)d_in[2];
  const float* bq   = (const float*)d_in[3];
  const float* Wk   = (const float*)d_in[4];
  const float* bk   = (const float*)d_in[5];
  const float* Wv   = (const float*)d_in[6];
  const float* bv   = (const float*)d_in[7];
  float* out = (float*)d_out;

  char* w = (char*)d_ws;
  u16*   xb    = (u16*)(w);                 // x bf16      [8192,1024]
  u16*   wT    = (u16*)(w + 16777216);      // [Wq;Wk;Wv]^T bf16 [3072,1024]
  float* biasC = (float*)(w + 23068672);    // concat bias [3072]
  u16*   QKV   = (u16*)(w + 23081088);      // Q,K bf16    [8192,3072]
  u16*   Vt    = (u16*)(w + 73414016);      // V^T bf16    [1024,8192]
  u16*   Pp    = (u16*)(w + 90191232);      // P bf16      [4,2048,2048]
  float* rowsum= (float*)(w + 123745664);   // row sums    [8192]

  prep<<<8192 + 3072 + 44, 256, 0, stream>>>(x, xb, Wq, Wk, Wv, wT, bq, bk, bv, biasC, rowsum);

  // QKV: [8192,1024] x [3072,1024]^T -> Q,K row-major + V^T
  gemm8<0><<<dim3(12, 32, 1), 512, 0, stream>>>(xb, wT, QKV, Vt, biasC, nullptr, nullptr,
      1024, 1024, 1024, 3072, 0, 0, 0, 1.0f);

  // scores: P = exp(QK^T/32 + mask), rowsum in-epilogue
  gemm8<2><<<dim3(8, 8, 4), 512, 0, stream>>>(QKV, QKV + 1024, Pp, nullptr, nullptr, rowsum,
      mask,
      1024, 3072, 3072, 2048,
      2048L * 3072, 2048L * 3072, 2048L * 2048, 0.03125f);

  // PV: out = (P V) / rowsum
  gemm_pv<<<dim3(8, 16, 4), 256, 0, stream>>>(Pp, Vt, out, rowsum,
      2048, 2048, 8192, 1024,
      2048L * 2048, 2048L, 2048L * 1024);
}

// Round 4
// 302.767 us; speedup vs baseline: 1.0346x; 1.0346x over previous
//
#include <hip/hip_runtime.h>
#include <hip/hip_bf16.h>
#include <stdint.h>

typedef unsigned short u16;
typedef __attribute__((ext_vector_type(4))) unsigned short u16x4;
typedef __attribute__((ext_vector_type(8))) short short8;
typedef __attribute__((ext_vector_type(4))) float f32x4;

__device__ inline u16 f2b(float f) {
  uint32_t u = __builtin_bit_cast(uint32_t, f);
  u += 0x7fffu + ((u >> 16) & 1u);   // RNE round to bf16
  return (u16)(u >> 16);
}
__device__ inline float b2f(u16 b) {
  return __builtin_bit_cast(float, (uint32_t)b << 16);
}

// ---------------- fused prep: x->bf16, W transpose+cvt, bias concat, rowsum zero --------
__global__ __launch_bounds__(256) void prep(
    const float* __restrict__ x, u16* __restrict__ xb,
    const float* __restrict__ Wq, const float* __restrict__ Wk,
    const float* __restrict__ Wv, u16* __restrict__ wT,
    const float* __restrict__ bq, const float* __restrict__ bk,
    const float* __restrict__ bv, float* __restrict__ biasC,
    float* __restrict__ rowsum) {
  __shared__ float tl[32][33];
  const int b = blockIdx.x;
  const int t = threadIdx.x;
  if (b < 8192) {
    long i = ((long)b * 256 + t) * 4;
    float4 v = *(const float4*)(x + i);
    u16x4 o = { f2b(v.x), f2b(v.y), f2b(v.z), f2b(v.w) };
    *(u16x4*)(xb + i) = o;
  } else if (b < 8192 + 3072) {
    const int bb = b - 8192;
    const int z = bb >> 10;            // 0..2 -> Wq/Wk/Wv
    const int tile = bb & 1023;
    const float* in = z == 0 ? Wq : (z == 1 ? Wk : Wv);
    u16* o = wT + (long)z * 1024 * 1024;
    const int c0 = (tile & 31) * 32, r0 = (tile >> 5) * 32;
    const int tx = t & 31, ty = t >> 5;   // 32 x 8
#pragma unroll
    for (int j = 0; j < 32; j += 8)
      tl[ty + j][tx] = in[(long)(r0 + ty + j) * 1024 + c0 + tx];
    __syncthreads();
#pragma unroll
    for (int j = 0; j < 32; j += 8)
      o[(long)(c0 + ty + j) * 1024 + r0 + tx] = f2b(tl[tx][ty + j]);
  } else {
    const int i = (b - 8192 - 3072) * 256 + t;
    if (i < 3072)
      biasC[i] = i < 1024 ? bq[i] : (i < 2048 ? bk[i - 1024] : bv[i - 2048]);
    else if (i < 3072 + 8192)
      rowsum[i - 3072] = 0.0f;
  }
}

__device__ inline void load_lds16(const void* g, void* l) {
  __builtin_amdgcn_global_load_lds((const __attribute__((address_space(1))) void*)g,
                                   (__attribute__((address_space(3))) void*)l, 16, 0, 0);
}

#define BAR  asm volatile("s_barrier" ::: "memory")
#define VM4  asm volatile("s_waitcnt vmcnt(4)" ::: "memory")
#define VM6  asm volatile("s_waitcnt vmcnt(6)" ::: "memory")

// ---------------- QKV: proven 128x128 kernel (2 blocks/CU) ----------------
#define BM 128
#define BN 128
#define BK 64

__global__ __launch_bounds__(256, 2) void gemm_qkv(
    const u16* __restrict__ A, const u16* __restrict__ Bt, u16* __restrict__ C,
    u16* __restrict__ vtOut, const float* __restrict__ bias,
    int K, int lda, int ldb, int ldc)
{
  __shared__ __align__(16) u16 lA[BM * BK];
  __shared__ __align__(16) u16 lB[BN * BK];

  const int t = threadIdx.x;
  const int lane = t & 63;
  const int wave = t >> 6;
  const int wr = wave >> 1, wc = wave & 1;
  const int m0 = blockIdx.y * BM, n0 = blockIdx.x * BN;

  const int srow = t >> 3;
  const int schunk = (t & 7) ^ (srow & 7);
  const u16* aS = A + (long)(m0 + srow) * lda + schunk * 8;
  const u16* bS = Bt + (long)(n0 + srow) * ldb + schunk * 8;

  f32x4 acc[4][4] = {};
  const int fr = lane & 15;
  const int q4 = lane >> 4;

  for (int k0 = 0; k0 < K; k0 += BK) {
    __syncthreads();
#pragma unroll
    for (int i = 0; i < 4; i++) {
      load_lds16(aS + k0 + (long)(i * 32) * lda, &lA[(i * 256 + t) * 8]);
      load_lds16(bS + k0 + (long)(i * 32) * ldb, &lB[(i * 256 + t) * 8]);
    }
    __syncthreads();
#pragma unroll
    for (int kk = 0; kk < 2; kk++) {
      const int ch = kk * 4 + q4;
      short8 aF[4], bF[4];
#pragma unroll
      for (int i = 0; i < 4; i++) {
        int row = wr * 64 + i * 16 + fr;
        aF[i] = *(const short8*)&lA[row * BK + ((ch ^ (row & 7)) * 8)];
      }
#pragma unroll
      for (int j = 0; j < 4; j++) {
        int row = wc * 64 + j * 16 + fr;
        bF[j] = *(const short8*)&lB[row * BK + ((ch ^ (row & 7)) * 8)];
      }
#pragma unroll
      for (int i = 0; i < 4; i++)
#pragma unroll
        for (int j = 0; j < 4; j++)
          acc[i][j] = __builtin_amdgcn_mfma_f32_16x16x32_bf16(aF[i], bF[j], acc[i][j], 0, 0, 0);
    }
  }

  const int r0 = q4 * 4;
#pragma unroll
  for (int i = 0; i < 4; i++) {
#pragma unroll
    for (int j = 0; j < 4; j++) {
      const int row = m0 + wr * 64 + i * 16 + r0;
      const int col = n0 + wc * 64 + j * 16 + fr;
      const float b = bias[col];
      if (col >= 2048) {
        u16x4 o = { f2b(acc[i][j][0] + b), f2b(acc[i][j][1] + b),
                    f2b(acc[i][j][2] + b), f2b(acc[i][j][3] + b) };
        *(u16x4*)(vtOut + (long)(col - 2048) * 8192 + row) = o;
      } else {
#pragma unroll
        for (int r = 0; r < 4; r++)
          C[(long)(row + r) * ldc + col] = f2b(acc[i][j][r] + b);
      }
    }
  }
}

// 16-MFMA cluster for the 8-phase kernel: quadrant (IH,JH), full K=64
#define MM8(IH, JH) do {                                                       \
  __builtin_amdgcn_s_setprio(1);                                               \
  _Pragma("unroll")                                                            \
  for (int i_ = 0; i_ < 4; i_++)                                               \
    _Pragma("unroll")                                                          \
    for (int j_ = 0; j_ < 2; j_++)                                             \
      _Pragma("unroll")                                                        \
      for (int kk_ = 0; kk_ < 2; kk_++)                                        \
        acc[(IH)*4 + i_][(JH)*2 + j_] = __builtin_amdgcn_mfma_f32_16x16x32_bf16( \
            aF[i_][kk_], bF[JH][j_][kk_], acc[(IH)*4 + i_][(JH)*2 + j_], 0, 0, 0); \
  __builtin_amdgcn_s_setprio(0);                                               \
} while (0)

// ---------------- scores: 256x256 8-phase (template-exact counted vmcnt) ----------------
// 8 waves = 2(M) x 4(N); per-wave 128x64 out. LDS dbuf A+B = 128 KB, chunk-XOR swizzle.
// Quadrants (00),(01),(11),(10); BOTH B-halves kept in regs -> no LDS re-reads;
// stage 1 half-tile/phase in stream order [A0,B0,B1,A1]; during tile t stage
// [t+1.A1, t+2.A0, t+2.B0, t+2.B1]; single vmcnt(6) at phase 4 (3 half-tiles in
// flight across barriers). Each staged half overwrites a region whose LDS reads
// completed at least one barrier earlier (A0 read P1, B0 read P1, B1 read P2;
// overwrites land at P2/P3/P4 respectively).
// Epilogue: P = exp(v*scale + mask) bf16; rowsum[row] += partial sums.
__global__ __launch_bounds__(512, 1) void gemm8s(
    const u16* __restrict__ A, const u16* __restrict__ Bt, u16* __restrict__ P,
    float* __restrict__ rsum, const float* __restrict__ maskG,
    int K, int lda, int ldb, int ldc,
    long sA_, long sB_, long sC_, float scale)
{
  const int z = blockIdx.z;
  A += z * sA_;
  Bt += z * sB_;
  const long cbase = z * sC_;

  __shared__ __align__(16) u16 sA[2][256 * 64];   // 64 KB
  __shared__ __align__(16) u16 sB[2][256 * 64];   // 64 KB

  const int t = threadIdx.x;
  const int lane = t & 63, wave = t >> 6;
  const int wr = wave >> 2, wc = wave & 3;        // 2 x 4 wave grid
  const int fr = lane & 15, q4 = lane >> 4;
  const int m0 = blockIdx.y * 256, n0 = blockIdx.x * 256;
  const int nT = K / 64;

  auto stA = [&](int half, int kt, int buf) {
    if (kt >= nT) kt -= nT;                        // tail clamp (staged, never read)
    const long ko = (long)kt * 64;
#pragma unroll
    for (int ii = 0; ii < 2; ii++) {
      int c = ii * 512 + t;
      int rr = c >> 3, slot = c & 7;
      int row = (rr < 64) ? (half * 64 + rr) : (128 + half * 64 + rr - 64);
      int gch = slot ^ (row & 7);
      load_lds16(A + (long)(m0 + row) * lda + ko + gch * 8,
                 &sA[buf][row * 64 + slot * 8]);
    }
  };
  auto stB = [&](int half, int kt, int buf) {
    if (kt >= nT) kt -= nT;
    const long ko = (long)kt * 64;
#pragma unroll
    for (int ii = 0; ii < 2; ii++) {
      int c = ii * 512 + t;
      int rr = c >> 3, slot = c & 7;
      int row = (rr >> 5) * 64 + half * 32 + (rr & 31);
      int gch = slot ^ (row & 7);
      load_lds16(Bt + (long)(n0 + row) * ldb + ko + gch * 8,
                 &sB[buf][row * 64 + slot * 8]);
    }
  };

  short8 aF[4][2];        // current A-half
  short8 bF[2][2][2];     // BOTH B-halves [half][frag][kstep]
  f32x4 acc[8][4] = {};

  auto rdA = [&](int half, int buf) {
#pragma unroll
    for (int i = 0; i < 4; i++) {
      int row = wr * 128 + half * 64 + i * 16 + fr;
#pragma unroll
      for (int kk = 0; kk < 2; kk++) {
        int ch = kk * 4 + q4;
        aF[i][kk] = *(const short8*)&sA[buf][row * 64 + ((ch ^ (row & 7)) * 8)];
      }
    }
  };
  auto rdB = [&](int half, int buf) {
#pragma unroll
    for (int j = 0; j < 2; j++) {
      int row = wc * 64 + half * 32 + j * 16 + fr;
#pragma unroll
      for (int kk = 0; kk < 2; kk++) {
        int ch = kk * 4 + q4;
        bF[half][j][kk] = *(const short8*)&sB[buf][row * 64 + ((ch ^ (row & 7)) * 8)];
      }
    }
  };

  // prologue: tile0 (4 half-tiles) -> vmcnt(4); tile1 A0,B0,B1 -> vmcnt(6)
  stA(0, 0, 0); stB(0, 0, 0); stB(1, 0, 0); stA(1, 0, 0);
  VM4;
  stA(0, 1, 1); stB(0, 1, 1); stB(1, 1, 1);
  VM6; BAR;

#pragma unroll 1
  for (int kt = 0; kt < nT; ++kt) {
    const int buf = kt & 1, nbuf = buf ^ 1;
    // P1: quadrant (0,0)
    rdA(0, buf); rdB(0, buf); stA(1, kt + 1, nbuf);
    BAR; MM8(0, 0); BAR;
    // P2: quadrant (0,1)
    rdB(1, buf);              stA(0, kt + 2, buf);
    BAR; MM8(0, 1); BAR;
    // P3: quadrant (1,1)
    rdA(1, buf);              stB(0, kt + 2, buf);
    BAR; MM8(1, 1); BAR;
    // P4: quadrant (1,0) — no ds_reads; single counted wait per tile
    stB(1, kt + 2, buf);
    BAR; MM8(1, 0); VM6; BAR;
  }

  // epilogue: C/D layout col = lane&15, row = (lane>>4)*4 + r
  const float* mk = maskG + (long)z * 2048 * 2048;
  u16* Pout = P + cbase;
  float* rz = rsum + (long)z * 2048;
#pragma unroll
  for (int i = 0; i < 8; i++) {
    const int row = m0 + wr * 128 + i * 16 + q4 * 4;
    float ml[4][4];
#pragma unroll
    for (int j = 0; j < 4; j++) {
      const int col = n0 + wc * 64 + j * 16 + fr;
#pragma unroll
      for (int r = 0; r < 4; r++)
        ml[j][r] = mk[(long)(row + r) * 2048 + col];   // 16 loads batched in flight
    }
    float rs[4] = {0.f, 0.f, 0.f, 0.f};
#pragma unroll
    for (int j = 0; j < 4; j++) {
      const int col = n0 + wc * 64 + j * 16 + fr;
#pragma unroll
      for (int r = 0; r < 4; r++) {
        float e = __expf(acc[i][j][r] * scale + ml[j][r]);
        Pout[(long)(row + r) * ldc + col] = f2b(e);
        rs[r] += e;
      }
    }
#pragma unroll
    for (int r = 0; r < 4; r++) {
      float s = rs[r];
      s += __shfl_xor(s, 1); s += __shfl_xor(s, 2);
      s += __shfl_xor(s, 4); s += __shfl_xor(s, 8);
      if (fr == 0) atomicAdd(&rz[row + r], s);
    }
  }
}

// ---------------- PV: proven 128x128 kernel, deferred-normalization epilogue ----------------
__global__ __launch_bounds__(256, 2) void gemm_pv(
    const u16* __restrict__ A, const u16* __restrict__ Bt, float* __restrict__ C,
    const float* __restrict__ rsum,
    int K, int lda, int ldb, int ldc, long sA_, long sB_, long sC_)
{
  const int z = blockIdx.z;
  A += z * sA_;
  Bt += z * sB_;
  const long cbase = z * sC_;

  __shared__ __align__(16) u16 lA[BM * BK];
  __shared__ __align__(16) u16 lB[BN * BK];

  const int t = threadIdx.x;
  const int lane = t & 63;
  const int wave = t >> 6;
  const int wr = wave >> 1, wc = wave & 1;
  const int m0 = blockIdx.y * BM, n0 = blockIdx.x * BN;

  const int srow = t >> 3;
  const int schunk = (t & 7) ^ (srow & 7);
  const u16* aS = A + (long)(m0 + srow) * lda + schunk * 8;
  const u16* bS = Bt + (long)(n0 + srow) * ldb + schunk * 8;

  f32x4 acc[4][4] = {};
  const int fr = lane & 15;
  const int q4 = lane >> 4;

  for (int k0 = 0; k0 < K; k0 += BK) {
    __syncthreads();
#pragma unroll
    for (int i = 0; i < 4; i++) {
      load_lds16(aS + k0 + (long)(i * 32) * lda, &lA[(i * 256 + t) * 8]);
      load_lds16(bS + k0 + (long)(i * 32) * ldb, &lB[(i * 256 + t) * 8]);
    }
    __syncthreads();
#pragma unroll
    for (int kk = 0; kk < 2; kk++) {
      const int ch = kk * 4 + q4;
      short8 aF[4], bF[4];
#pragma unroll
      for (int i = 0; i < 4; i++) {
        int row = wr * 64 + i * 16 + fr;
        aF[i] = *(const short8*)&lA[row * BK + ((ch ^ (row & 7)) * 8)];
      }
#pragma unroll
      for (int j = 0; j < 4; j++) {
        int row = wc * 64 + j * 16 + fr;
        bF[j] = *(const short8*)&lB[row * BK + ((ch ^ (row & 7)) * 8)];
      }
#pragma unroll
      for (int i = 0; i < 4; i++)
#pragma unroll
        for (int j = 0; j < 4; j++)
          acc[i][j] = __builtin_amdgcn_mfma_f32_16x16x32_bf16(aF[i], bF[j], acc[i][j], 0, 0, 0);
    }
  }

  const int r0 = q4 * 4;
  const float* lz = rsum + (long)z * 2048;
#pragma unroll
  for (int i = 0; i < 4; i++) {
    const int row = m0 + wr * 64 + i * 16 + r0;
    float inv[4];
#pragma unroll
    for (int r = 0; r < 4; r++) inv[r] = 1.0f / lz[row + r];
#pragma unroll
    for (int j = 0; j < 4; j++) {
      const int col = n0 + wc * 64 + j * 16 + fr;
#pragma unroll
      for (int r = 0; r < 4; r++)
        C[cbase + (long)(row + r) * ldc + col] = acc[i][j][r] * inv[r];
    }
  }
}

// ---------------- launch ----------------
extern "C" void kernel_launch(void* const* d_in, const int* in_sizes, int n_in,
                              void* d_out, int out_size, void* d_ws, size_t ws_size,
                              hipStream_t stream) {
  const float* x    = (const float*)d_in[0];   // [4,2048,1024]
  const float* mask = (const float*)d_in[1];   // [4,2048,2048]
  const float* Wq   = (const float*)d_in[2];
  const float* bq   = (const float*)d_in[3];
  const float* Wk   = (const float*)d_in[4];
  const float* bk   = (const float*)d_in[5];
  const float* Wv   = (const float*)d_in[6];
  const float* bv   = (const float*)d_in[7];
  float* out = (float*)d_out;

  char* w = (char*)d_ws;
  u16*   xb    = (u16*)(w);                 // x bf16      [8192,1024]
  u16*   wT    = (u16*)(w + 16777216);      // [Wq;Wk;Wv]^T bf16 [3072,1024]
  float* biasC = (float*)(w + 23068672);    // concat bias [3072]
  u16*   QKV   = (u16*)(w + 23081088);      // Q,K bf16    [8192,3072]
  u16*   Vt    = (u16*)(w + 73414016);      // V^T bf16    [1024,8192]
  u16*   Pp    = (u16*)(w + 90191232);      // P bf16      [4,2048,2048]
  float* rowsum= (float*)(w + 123745664);   // row sums    [8192]

  prep<<<8192 + 3072 + 44, 256, 0, stream>>>(x, xb, Wq, Wk, Wv, wT, bq, bk, bv, biasC, rowsum);

  // QKV: proven 128² kernel — [8192,1024] x [3072,1024]^T -> Q,K + V^T
  gemm_qkv<<<dim3(24, 64, 1), 256, 0, stream>>>(xb, wT, QKV, Vt, biasC,
      1024, 1024, 1024, 3072);

  // scores: 256² 8-phase — P = exp(QK^T/32 + mask), rowsum in-epilogue
  gemm8s<<<dim3(8, 8, 4), 512, 0, stream>>>(QKV, QKV + 1024, Pp, rowsum, mask,
      1024, 3072, 3072, 2048,
      2048L * 3072, 2048L * 3072, 2048L * 2048, 0.03125f);

  // PV: out = (P V) / rowsum
  gemm_pv<<<dim3(8, 16, 4), 256, 0, stream>>>(Pp, Vt, out, rowsum,
      2048, 2048, 8192, 1024,
      2048L * 2048, 2048L, 2048L * 1024);
}